// Round 11
// baseline (626.811 us; speedup 1.0000x reference)
//
#include <hip/hip_runtime.h>
#include <hip/hip_cooperative_groups.h>
#include <stdint.h>

namespace cg = cooperative_groups;

// Problem constants (from reference setup_inputs)
#define Bg    128
#define NPG   512
#define Cc    128
#define EPG   8192
#define Nn    (Bg*NPG)      // 65536
#define Ee    (Bg*EPG)      // 1048576
#define Kk    410           // ceil(0.8*512)
#define NKk   (Bg*Kk)       // 52480
#define ROFFS_STRIDE 411
#define SLOPE 0.2f
#define GRD   1024          // cooperative grid: 1024 blocks x 256 thr (<=8 blk/CU, 2x margin)
#define NWAVE (GRD*4)       // 4096 waves

typedef float f2v __attribute__((ext_vector_type(2)));

// ---------- exclusive scan of 512 ints with 256 threads ----------
__device__ __forceinline__ void scan512_256(int* buf, int* ws) {
  int t = threadIdx.x, lane = t & 63, w = t >> 6;   // 4 waves
  int v0 = buf[2 * t], v1 = buf[2 * t + 1];
  int p = v0 + v1;
  int s = p;
  #pragma unroll
  for (int d = 1; d < 64; d <<= 1) { int u = __shfl_up(s, d, 64); if (lane >= d) s += u; }
  if (lane == 63) ws[w] = s;
  __syncthreads();
  if (t < 4) {
    int u = ws[t];
    #pragma unroll
    for (int d = 1; d < 4; d <<= 1) { int u2 = __shfl_up(u, d, 64); if (t >= d) u += u2; }
    ws[t] = u;
  }
  __syncthreads();
  int excl = s - p + (w ? ws[w - 1] : 0);
  buf[2 * t]     = excl;
  buf[2 * t + 1] = excl + v0;
  __syncthreads();
}

__global__ __launch_bounds__(256, 8) void k_mega(
    const float* __restrict__ x, const int* __restrict__ row, const int* __restrict__ col,
    const float* __restrict__ attr, const float* __restrict__ att,
    int* __restrict__ offs, int* __restrict__ csr_src, float* __restrict__ csr_coef,
    float* __restrict__ score, int* __restrict__ roffs, int* __restrict__ icol,
    float* __restrict__ ival, float* __restrict__ e1, float* __restrict__ e2,
    float* __restrict__ o_xpool, float* __restrict__ o_nrow, float* __restrict__ o_ncol,
    float* __restrict__ o_attn, float* __restrict__ o_batch) {
  cg::grid_group grid = cg::this_grid();
  __shared__ union {
    struct { int cnt[512]; int cur[512]; float deg[512]; float dis[512]; } a;     // 8 KB
    struct { unsigned long long keys[512]; int mapL[512]; int rcnt[512];
             int rcur[512]; uint16_t permL[512]; } c;                              // 11.25 KB
    struct { float buf[4][416]; } e;                                               // 6.5 KB
  } sm;
  __shared__ int ws[8];
  int t = threadIdx.x, lane = t & 63, w4 = t >> 6;
  int wid = blockIdx.x * 4 + w4;                    // global wave id, 0..4095

  // ============ A: per-graph {deg, dis, in-count, scan, dst-CSR} (blocks 0..127) ============
  if (blockIdx.x < Bg) {
    int g = blockIdx.x, base = g * NPG;
    const int*   rowg  = row  + g * EPG;
    const int*   colg  = col  + g * EPG;
    const float* attrg = attr + g * EPG;
    for (int i = t; i < NPG; i += 256) { sm.a.cnt[i] = 0; sm.a.deg[i] = 0.f; }
    __syncthreads();
    for (int i = t; i < EPG; i += 256) {
      atomicAdd(&sm.a.cnt[colg[i] - base], 1);
      atomicAdd(&sm.a.deg[rowg[i] - base], attrg[i]);
    }
    __syncthreads();
    for (int i = t; i < NPG; i += 256) {
      float d = sm.a.deg[i];
      sm.a.dis[i] = (d > 0.f) ? rsqrtf(fmaxf(d, 1e-12f)) : 0.f;
    }
    scan512_256(sm.a.cnt, ws);                      // cnt := exclusive offsets
    for (int i = t; i < NPG; i += 256) {
      offs[base + i] = g * EPG + sm.a.cnt[i];
      sm.a.cur[i] = sm.a.cnt[i];
    }
    if (t == 0) offs[base + NPG] = g * EPG + EPG;   // sentinel (== next block's entry 0)
    __syncthreads();
    for (int i = t; i < EPG; i += 256) {
      int s = rowg[i] - base, c = colg[i] - base;
      int slot = atomicAdd(&sm.a.cur[c], 1);
      csr_src[g * EPG + slot]  = rowg[i];           // global src node id
      csr_coef[g * EPG + slot] = sm.a.dis[s] * attrg[i] * sm.a.dis[c];
    }
  }
  grid.sync();

  // ============ B: score, full-wave float2 gather, 4-way unrolled (grid-stride waves) ============
  {
    const float2* xp = (const float2*)x;
    for (int node = wid; node < Nn; node += NWAVE) {
      float2 xv = xp[(size_t)node * 64 + lane];
      int s0 = offs[node], s1 = offs[node + 1];
      float a0 = 0.f, a1 = 0.f, b0 = 0.f, b1 = 0.f;
      int s = s0;
      for (; s + 4 <= s1; s += 4) {
        int   i0 = csr_src[s],   i1 = csr_src[s+1],  i2 = csr_src[s+2],  i3 = csr_src[s+3];
        float c0 = csr_coef[s],  c1 = csr_coef[s+1], c2 = csr_coef[s+2], c3 = csr_coef[s+3];
        float2 v0 = xp[(size_t)i0 * 64 + lane];
        float2 v1 = xp[(size_t)i1 * 64 + lane];
        float2 v2 = xp[(size_t)i2 * 64 + lane];
        float2 v3 = xp[(size_t)i3 * 64 + lane];
        a0 += c0 * v0.x; a1 += c0 * v0.y;
        b0 += c1 * v1.x; b1 += c1 * v1.y;
        a0 += c2 * v2.x; a1 += c2 * v2.y;
        b0 += c3 * v3.x; b1 += c3 * v3.y;
      }
      for (; s < s1; ++s) {
        int i0 = csr_src[s]; float c0 = csr_coef[s];
        float2 v0 = xp[(size_t)i0 * 64 + lane];
        a0 += c0 * v0.x; a1 += c0 * v0.y;
      }
      float v = fabsf(xv.x - a0 - b0) + fabsf(xv.y - a1 - b1);
      #pragma unroll
      for (int d = 32; d; d >>= 1) v += __shfl_xor(v, d, 64);
      if (lane == 0) score[node] = v;
    }
  }
  grid.sync();

  // ============ C: top-k sort + induced CSR + feat (blocks 0..127) ============
  if (blockIdx.x < Bg) {
    int g = blockIdx.x, base = g * NPG;
    const int*   rowg  = row  + g * EPG;
    const int*   colg  = col  + g * EPG;
    const float* attrg = attr + g * EPG;
    for (int i = t; i < NPG; i += 256) {
      float sc = score[base + i];
      unsigned u = __float_as_uint(sc);
      unsigned ord = (u & 0x80000000u) ? ~u : (u | 0x80000000u);
      sm.c.keys[i] = ((unsigned long long)(~ord) << 32) | (unsigned)i;  // stable desc
    }
    for (int k2 = 2; k2 <= 512; k2 <<= 1) {
      for (int j2 = k2 >> 1; j2 > 0; j2 >>= 1) {
        __syncthreads();
        for (int vt = t; vt < 512; vt += 256) {
          int ixj = vt ^ j2;
          if (ixj > vt) {
            unsigned long long a = sm.c.keys[vt], b = sm.c.keys[ixj];
            bool up = ((vt & k2) == 0);
            if ((a > b) == up) { sm.c.keys[vt] = b; sm.c.keys[ixj] = a; }
          }
        }
      }
    }
    __syncthreads();
    for (int i = t; i < NPG; i += 256) {
      int local = (int)(sm.c.keys[i] & 0xFFFFFFFFu);
      sm.c.mapL[local] = (i < Kk) ? i : -1;
      if (i < Kk) {
        sm.c.permL[i] = (uint16_t)local;
        o_batch[g * Kk + i] = (float)g;
      }
      sm.c.rcnt[i] = 0;
    }
    __syncthreads();
    for (int i = t; i < EPG; i += 256) {
      int mr = sm.c.mapL[rowg[i] - base], mc = sm.c.mapL[colg[i] - base];
      if (mr >= 0 && mc >= 0) atomicAdd(&sm.c.rcnt[mr], 1);
    }
    __syncthreads();
    scan512_256(sm.c.rcnt, ws);
    for (int i = t; i <= Kk; i += 256) roffs[g * ROFFS_STRIDE + i] = g * EPG + sm.c.rcnt[i];
    for (int i = t; i < NPG; i += 256) sm.c.rcur[i] = sm.c.rcnt[i];
    __syncthreads();
    for (int i = t; i < EPG; i += 256) {
      int mr = sm.c.mapL[rowg[i] - base], mc = sm.c.mapL[colg[i] - base];
      if (mr >= 0 && mc >= 0) {
        int slot = atomicAdd(&sm.c.rcur[mr], 1);
        icol[g * EPG + slot] = mc;
        ival[g * EPG + slot] = attrg[i];
      }
    }
    __syncthreads();
    // ---- feat: x_pool gather + e1/e2 GEMV (permL in LDS, no extra sync) ----
    const float2* att2 = (const float2*)att;
    float2 a1v = att2[lane], a2v = att2[64 + lane];
    const float2* x2 = (const float2*)x;
    for (int j = w4; j < Kk; j += 4) {
      int lsrc = sm.c.permL[j];
      float2 xv = x2[(size_t)(base + lsrc) * 64 + lane];
      ((float2*)o_xpool)[(size_t)(g * Kk + j) * 64 + lane] = xv;
      float s1 = xv.x * a1v.x + xv.y * a1v.y;
      float s2 = xv.x * a2v.x + xv.y * a2v.y;
      #pragma unroll
      for (int d = 32; d; d >>= 1) { s1 += __shfl_xor(s1, d, 64); s2 += __shfl_xor(s2, d, 64); }
      if (lane == 0) { e1[g * Kk + j] = s1; e2[g * Kk + j] = s2; }
    }
  }
  grid.sync();

  // ============ E: W build + softmax + attn/new_row/new_col (grid-stride waves) ============
  {
    float* bw = sm.e.buf[w4];
    for (int rowid = wid; rowid < NKk; rowid += NWAVE) {
      int b = rowid / Kk;
      int r = rowid - b * Kk;
      float ev = e1[rowid];
      const float* e2g = e2 + b * Kk;
      for (int j = lane; j < Kk; j += 64) {
        float v = ev + e2g[j];
        bw[j] = (v > 0.f) ? v : SLOPE * v;
      }
      int t0 = roffs[b * ROFFS_STRIDE + r], t1 = roffs[b * ROFFS_STRIDE + r + 1];
      for (int p = t0 + lane; p < t1; p += 64)
        atomicAdd(&bw[icol[p]], ival[p]);            // LAMB = 1.0
      float m = -1e30f;
      for (int j = lane; j < Kk; j += 64) m = fmaxf(m, bw[j]);
      #pragma unroll
      for (int d = 32; d; d >>= 1) m = fmaxf(m, __shfl_xor(m, d, 64));
      float s = 0.f;
      for (int j = lane; j < Kk; j += 64) {
        float ex = __expf(bw[j] - m);
        bw[j] = ex;
        s += ex;
      }
      #pragma unroll
      for (int d = 32; d; d >>= 1) s += __shfl_xor(s, d, 64);
      float inv = 1.f / s;
      size_t fb = (size_t)rowid * Kk;
      f2v* ap = (f2v*)(o_attn + fb);
      f2v* nr = (f2v*)(o_nrow + fb);
      f2v* nc = (f2v*)(o_ncol + fb);
      float frow  = (float)rowid;
      float cbase = (float)(b * Kk);
      for (int p = lane; p < Kk / 2; p += 64) {
        int j = 2 * p;
        f2v av; av.x = bw[j] * inv; av.y = bw[j + 1] * inv;
        f2v rv; rv.x = frow; rv.y = frow;
        f2v cv; cv.x = cbase + j; cv.y = cbase + j + 1;
        __builtin_nontemporal_store(av, ap + p);
        __builtin_nontemporal_store(rv, nr + p);
        __builtin_nontemporal_store(cv, nc + p);
      }
    }
  }
}

// ---------------- host launch ----------------
extern "C" void kernel_launch(void* const* d_in, const int* in_sizes, int n_in,
                              void* d_out, int out_size, void* d_ws, size_t ws_size,
                              hipStream_t stream) {
  const float* x    = (const float*)d_in[0];
  const int*   row  = (const int*)d_in[1];
  const int*   col  = row + Ee;
  const float* attr = (const float*)d_in[2];
  const float* att  = (const float*)d_in[4];

  char* ws = (char*)d_ws;
  size_t off = 0;
  auto alloc = [&](size_t bytes) { char* p = ws + off; off = (off + bytes + 255) & ~(size_t)255; return p; };
  int*   offs     = (int*)  alloc((size_t)(Nn + 1) * 4);
  int*   csr_src  = (int*)  alloc((size_t)Ee * 4);
  float* csr_coef = (float*)alloc((size_t)Ee * 4);
  float* score    = (float*)alloc((size_t)Nn * 4);
  int*   roffs    = (int*)  alloc((size_t)Bg * ROFFS_STRIDE * 4);
  int*   icol     = (int*)  alloc((size_t)Ee * 4);
  float* ival     = (float*)alloc((size_t)Ee * 4);
  float* e1       = (float*)alloc((size_t)NKk * 4);
  float* e2       = (float*)alloc((size_t)NKk * 4);

  // output layout: x_pool | new_row | new_col | attn | batch_pool (all fp32)
  float* out      = (float*)d_out;
  float* o_xpool  = out;
  float* o_nrow   = o_xpool + (size_t)NKk * Cc;
  float* o_ncol   = o_nrow + (size_t)NKk * Kk;
  float* o_attn   = o_ncol + (size_t)NKk * Kk;
  float* o_batch  = o_attn + (size_t)NKk * Kk;

  void* args[] = {
    (void*)&x, (void*)&row, (void*)&col, (void*)&attr, (void*)&att,
    (void*)&offs, (void*)&csr_src, (void*)&csr_coef, (void*)&score,
    (void*)&roffs, (void*)&icol, (void*)&ival, (void*)&e1, (void*)&e2,
    (void*)&o_xpool, (void*)&o_nrow, (void*)&o_ncol, (void*)&o_attn, (void*)&o_batch
  };
  hipLaunchCooperativeKernel((const void*)k_mega, dim3(GRD), dim3(256), args, 0, stream);
}

// Round 12
// 195.737 us; speedup vs baseline: 3.2023x; 3.2023x over previous
//
#include <hip/hip_runtime.h>
#include <stdint.h>

// Problem constants (from reference setup_inputs)
#define Bg    128
#define NPG   512
#define Cc    128
#define EPG   8192
#define Nn    (Bg*NPG)      // 65536
#define Ee    (Bg*EPG)      // 1048576
#define Kk    410           // ceil(0.8*512)
#define NKk   (Bg*Kk)       // 52480
#define ROFFS_STRIDE 411
#define SLOPE 0.2f
#define GPB   103           // graph-aligned blocks per graph for feat/softmax (103*4 >= 410)

typedef float f2v __attribute__((ext_vector_type(2)));

// ---------- LDS exclusive scan over 512 ints, 512 threads ----------
__device__ __forceinline__ void scan512(int* buf, int* ws) {
  int t = threadIdx.x, lane = t & 63, w = t >> 6;
  int v = buf[t];
  int s = v;
  #pragma unroll
  for (int d = 1; d < 64; d <<= 1) { int u = __shfl_up(s, d, 64); if (lane >= d) s += u; }
  if (lane == 63) ws[w] = s;
  __syncthreads();
  if (t < 8) {
    int u = ws[t];
    #pragma unroll
    for (int d = 1; d < 8; d <<= 1) { int u2 = __shfl_up(u, d, 64); if (t >= d) u += u2; }
    ws[t] = u;
  }
  __syncthreads();
  int excl = s - v + (w ? ws[w - 1] : 0);
  buf[t] = excl;
  __syncthreads();
}

// ---------- K1: per-graph {deg, dis, count, scan, packed dst-CSR} ----------
// Graph remap g=(bb&7)*16+(bb>>3): graph g runs on XCD g/16 — the SAME XCD
// that k_score's swizzle assigns g's consumer blocks to (csr output stays
// in the right per-XCD L2). csrp[e] = {src_row_byte_offset, coef_bits}.
__global__ __launch_bounds__(512) void k_build_csr(const int* __restrict__ row,
                                                   const int* __restrict__ col,
                                                   const float* __restrict__ attr,
                                                   int* __restrict__ offs,
                                                   int2* __restrict__ csrp) {
  __shared__ int cnt[512];
  __shared__ int cur[512];
  __shared__ float degL[512];
  __shared__ float disL[512];
  __shared__ int ws[8];
  int bb = blockIdx.x;
  int g = (bb & 7) * 16 + (bb >> 3);              // bijective, XCD-aligned
  int t = threadIdx.x, base = g * NPG;
  const int*   rowg  = row  + g * EPG;
  const int*   colg  = col  + g * EPG;
  const float* attrg = attr + g * EPG;
  cnt[t] = 0; degL[t] = 0.f;
  __syncthreads();
  for (int i = t; i < EPG; i += 512) {
    atomicAdd(&cnt[colg[i] - base], 1);
    atomicAdd(&degL[rowg[i] - base], attrg[i]);
  }
  __syncthreads();
  float d = degL[t];
  disL[t] = (d > 0.f) ? rsqrtf(fmaxf(d, 1e-12f)) : 0.f;
  scan512(cnt, ws);
  offs[base + t] = g * EPG + cnt[t];
  if (t == 0) offs[base + NPG] = g * EPG + EPG;   // benign duplicate of next entry
  cur[t] = cnt[t];
  __syncthreads();
  for (int i = t; i < EPG; i += 512) {
    int s = rowg[i] - base, c = colg[i] - base;
    int slot = atomicAdd(&cur[c], 1);
    int2 p;
    p.x = rowg[i] << 9;                            // src * 512 B (fp32 row stride)
    p.y = __float_as_int(disL[s] * attrg[i] * disL[c]);
    csrp[g * EPG + slot] = p;
  }
}

// ---------- K2: score, packed-CSR float2 gather, 4-way unrolled ----------
// one wave per node, 2 ch/lane; XCD-chunked swizzle (graph g on XCD g/16).
__global__ __launch_bounds__(256) void k_score(const float* __restrict__ x,
                                               const int* __restrict__ offs,
                                               const int2* __restrict__ csrp,
                                               float* __restrict__ score) {
  int bb = blockIdx.x;
  int wg = ((bb & 7) << 11) | (bb >> 3);          // bijective over 16384
  int lane = threadIdx.x & 63;
  int node = wg * 4 + (threadIdx.x >> 6);
  const char* xb = (const char*)x;
  int lo8 = lane * 8;
  float2 xv = *(const float2*)(xb + ((size_t)node << 9) + lo8);
  int s0 = offs[node], s1 = offs[node + 1];
  float a0 = 0.f, a1 = 0.f, b0 = 0.f, b1 = 0.f;
  int s = s0;
  for (; s + 4 <= s1; s += 4) {
    int2 p0 = csrp[s], p1 = csrp[s+1], p2 = csrp[s+2], p3 = csrp[s+3];
    float2 v0 = *(const float2*)(xb + p0.x + lo8);
    float2 v1 = *(const float2*)(xb + p1.x + lo8);
    float2 v2 = *(const float2*)(xb + p2.x + lo8);
    float2 v3 = *(const float2*)(xb + p3.x + lo8);
    float c0 = __int_as_float(p0.y), c1 = __int_as_float(p1.y);
    float c2 = __int_as_float(p2.y), c3 = __int_as_float(p3.y);
    a0 += c0 * v0.x; a1 += c0 * v0.y;
    b0 += c1 * v1.x; b1 += c1 * v1.y;
    a0 += c2 * v2.x; a1 += c2 * v2.y;
    b0 += c3 * v3.x; b1 += c3 * v3.y;
  }
  for (; s < s1; ++s) {
    int2 p0 = csrp[s];
    float2 v0 = *(const float2*)(xb + p0.x + lo8);
    float c0 = __int_as_float(p0.y);
    a0 += c0 * v0.x; a1 += c0 * v0.y;
  }
  float v = fabsf(xv.x - a0 - b0) + fabsf(xv.y - a1 - b1);
  #pragma unroll
  for (int d = 32; d; d >>= 1) v += __shfl_xor(v, d, 64);
  if (lane == 0) score[node] = v;
}

// ---------- K3: per-graph {stable top-k bitonic, perm/batch, induced CSR} ----------
__global__ __launch_bounds__(512) void k_topk_induced(const float* __restrict__ score,
                                                      const int* __restrict__ row,
                                                      const int* __restrict__ col,
                                                      const float* __restrict__ attr,
                                                      int* __restrict__ perm,
                                                      float* __restrict__ batch_out,
                                                      int* __restrict__ roffs,
                                                      int* __restrict__ icol,
                                                      float* __restrict__ ival) {
  __shared__ unsigned long long keys[512];
  __shared__ int mapL[512];
  __shared__ int rcnt[512];
  __shared__ int rcur[512];
  __shared__ int ws[8];
  int bb = blockIdx.x;
  int g = (bb & 7) * 16 + (bb >> 3);              // XCD-aligned with score's writers
  int t = threadIdx.x, base = g * NPG;
  float sc = score[base + t];
  unsigned u = __float_as_uint(sc);
  unsigned ord = (u & 0x80000000u) ? ~u : (u | 0x80000000u);
  keys[t] = ((unsigned long long)(~ord) << 32) | (unsigned)t;
  for (int k2 = 2; k2 <= 512; k2 <<= 1) {
    for (int j2 = k2 >> 1; j2 > 0; j2 >>= 1) {
      __syncthreads();
      int ixj = t ^ j2;
      if (ixj > t) {
        unsigned long long a = keys[t], b = keys[ixj];
        bool up = ((t & k2) == 0);
        if ((a > b) == up) { keys[t] = b; keys[ixj] = a; }
      }
    }
  }
  __syncthreads();
  int local = (int)(keys[t] & 0xFFFFFFFFu);
  mapL[local] = (t < Kk) ? t : -1;
  if (t < Kk) {
    perm[g * Kk + t] = base + local;
    batch_out[g * Kk + t] = (float)g;
  }
  rcnt[t] = 0;
  __syncthreads();
  const int*   rowg  = row  + g * EPG;
  const int*   colg  = col  + g * EPG;
  const float* attrg = attr + g * EPG;
  for (int i = t; i < EPG; i += 512) {
    int mr = mapL[rowg[i] - base], mc = mapL[colg[i] - base];
    if (mr >= 0 && mc >= 0) atomicAdd(&rcnt[mr], 1);
  }
  __syncthreads();
  scan512(rcnt, ws);
  if (t <= Kk) roffs[g * ROFFS_STRIDE + t] = g * EPG + rcnt[t];
  rcur[t] = rcnt[t];
  __syncthreads();
  for (int i = t; i < EPG; i += 512) {
    int mr = mapL[rowg[i] - base], mc = mapL[colg[i] - base];
    if (mr >= 0 && mc >= 0) {
      int slot = atomicAdd(&rcur[mr], 1);
      icol[g * EPG + slot] = mc;
      ival[g * EPG + slot] = attrg[i];
    }
  }
}

// ---------- K4: x_pool gather + e1/e2 GEMV, graph-aligned blocks ----------
// 103 blocks/graph x 4 rows; bb=(x8,q): g = x8*16 + q/103 (XCD-aligned).
__global__ __launch_bounds__(256) void k_feat(const float* __restrict__ x,
                                              const int* __restrict__ perm,
                                              const float* __restrict__ att,
                                              float* __restrict__ e1,
                                              float* __restrict__ e2,
                                              float* __restrict__ xpool) {
  int bb = blockIdx.x;
  int x8 = bb & 7, q = bb >> 3;                   // q in [0, 16*103)
  int g = x8 * 16 + q / GPB;
  int blk = q % GPB;
  int lane = threadIdx.x & 63, w = threadIdx.x >> 6;
  int r = blk * 4 + w;
  if (r >= Kk) return;
  int j = g * Kk + r;
  int gsrc = perm[j];
  float2 xv = ((const float2*)x)[(size_t)gsrc * 64 + lane];
  ((float2*)xpool)[(size_t)j * 64 + lane] = xv;
  float2 a1 = ((const float2*)att)[lane];
  float2 a2 = ((const float2*)(att + Cc))[lane];
  float s1 = xv.x * a1.x + xv.y * a1.y;
  float s2 = xv.x * a2.x + xv.y * a2.y;
  #pragma unroll
  for (int d = 32; d; d >>= 1) { s1 += __shfl_xor(s1, d, 64); s2 += __shfl_xor(s2, d, 64); }
  if (lane == 0) { e1[j] = s1; e2[j] = s2; }
}

// ---------- K5: softmax, graph-aligned blocks, e2 staged in LDS ----------
__global__ __launch_bounds__(256) void k_softmax(const float* __restrict__ e1,
                                                 const float* __restrict__ e2,
                                                 const int* __restrict__ roffs,
                                                 const int* __restrict__ icol,
                                                 const float* __restrict__ ival,
                                                 float* __restrict__ attn,
                                                 float* __restrict__ nrow,
                                                 float* __restrict__ ncol) {
  __shared__ float e2s[412];
  __shared__ float buf[4][416];
  int bb = blockIdx.x;
  int x8 = bb & 7, q = bb >> 3;
  int g = x8 * 16 + q / GPB;
  int blk = q % GPB;
  int t = threadIdx.x, lane = t & 63, w = t >> 6;
  for (int i = t; i < Kk; i += 256) e2s[i] = e2[g * Kk + i];
  __syncthreads();
  int r = blk * 4 + w;
  if (r >= Kk) return;
  int rowid = g * Kk + r;
  float* bw = buf[w];
  float ev = e1[rowid];
  for (int j = lane; j < Kk; j += 64) {
    float v = ev + e2s[j];
    bw[j] = (v > 0.f) ? v : SLOPE * v;
  }
  int t0 = roffs[g * ROFFS_STRIDE + r], t1 = roffs[g * ROFFS_STRIDE + r + 1];
  for (int p = t0 + lane; p < t1; p += 64)
    atomicAdd(&bw[icol[p]], ival[p]);              // LAMB = 1.0
  float m = -1e30f;
  for (int j = lane; j < Kk; j += 64) m = fmaxf(m, bw[j]);
  #pragma unroll
  for (int d = 32; d; d >>= 1) m = fmaxf(m, __shfl_xor(m, d, 64));
  float s = 0.f;
  for (int j = lane; j < Kk; j += 64) {
    float ex = __expf(bw[j] - m);
    bw[j] = ex;
    s += ex;
  }
  #pragma unroll
  for (int d = 32; d; d >>= 1) s += __shfl_xor(s, d, 64);
  float inv = 1.f / s;
  size_t fb = (size_t)rowid * Kk;
  f2v* ap = (f2v*)(attn + fb);
  f2v* nr = (f2v*)(nrow + fb);
  f2v* nc = (f2v*)(ncol + fb);
  float frow  = (float)rowid;
  float cbase = (float)(g * Kk);
  for (int p = lane; p < Kk / 2; p += 64) {
    int j = 2 * p;
    f2v av; av.x = bw[j] * inv; av.y = bw[j + 1] * inv;
    f2v rv; rv.x = frow; rv.y = frow;
    f2v cv; cv.x = cbase + j; cv.y = cbase + j + 1;
    __builtin_nontemporal_store(av, ap + p);
    __builtin_nontemporal_store(rv, nr + p);
    __builtin_nontemporal_store(cv, nc + p);
  }
}

// ---------------- host launch ----------------
extern "C" void kernel_launch(void* const* d_in, const int* in_sizes, int n_in,
                              void* d_out, int out_size, void* d_ws, size_t ws_size,
                              hipStream_t stream) {
  const float* x    = (const float*)d_in[0];
  const int*   row  = (const int*)d_in[1];
  const int*   col  = row + Ee;
  const float* attr = (const float*)d_in[2];
  const float* att  = (const float*)d_in[4];

  char* ws = (char*)d_ws;
  size_t off = 0;
  auto alloc = [&](size_t bytes) { char* p = ws + off; off = (off + bytes + 255) & ~(size_t)255; return p; };
  int*   offs     = (int*)  alloc((size_t)(Nn + 1) * 4);
  int2*  csrp     = (int2*) alloc((size_t)Ee * 8);
  float* score    = (float*)alloc((size_t)Nn * 4);
  int*   perm     = (int*)  alloc((size_t)NKk * 4);
  int*   roffs    = (int*)  alloc((size_t)Bg * ROFFS_STRIDE * 4);
  int*   icol     = (int*)  alloc((size_t)Ee * 4);
  float* ival     = (float*)alloc((size_t)Ee * 4);
  float* e1       = (float*)alloc((size_t)NKk * 4);
  float* e2       = (float*)alloc((size_t)NKk * 4);

  // output layout: x_pool | new_row | new_col | attn | batch_pool (all fp32)
  float* out      = (float*)d_out;
  float* o_xpool  = out;
  float* o_nrow   = o_xpool + (size_t)NKk * Cc;
  float* o_ncol   = o_nrow + (size_t)NKk * Kk;
  float* o_attn   = o_ncol + (size_t)NKk * Kk;
  float* o_batch  = o_attn + (size_t)NKk * Kk;

  k_build_csr  <<<Bg,       512, 0, stream>>>(row, col, attr, offs, csrp);
  k_score      <<<Nn / 4,   256, 0, stream>>>(x, offs, csrp, score);
  k_topk_induced<<<Bg,      512, 0, stream>>>(score, row, col, attr, perm, o_batch, roffs, icol, ival);
  k_feat       <<<Bg * GPB, 256, 0, stream>>>(x, perm, att, e1, e2, o_xpool);
  k_softmax    <<<Bg * GPB, 256, 0, stream>>>(e1, e2, roffs, icol, ival, o_attn, o_nrow, o_ncol);
}